// Round 5
// baseline (247.780 us; speedup 1.0000x reference)
//
#include <hip/hip_runtime.h>

#define SEQ 4096
#define DM 1024
#define NH 16
#define DK 64
#define NTW 3  // key tiles per wave (4 waves x 3 tiles x 32 keys = 384 >= 302 span)

typedef _Float16 half8 __attribute__((ext_vector_type(8)));
typedef _Float16 half4v __attribute__((ext_vector_type(4)));
typedef float f32x4 __attribute__((ext_vector_type(4)));

#define MFMA16(a, b, c) __builtin_amdgcn_mfma_f32_16x16x32_f16((a), (b), (c), 0, 0, 0)
#define GLOAD_LDS(g, l)                                                              \
    __builtin_amdgcn_global_load_lds((const __attribute__((address_space(1))) void*)(g), \
                                     (__attribute__((address_space(3))) void*)(l), 16, 0, 0)

// ---------------- fp32 -> fp16 conversion (7 tensors in one launch) ----------------
__global__ void cvt_all(const float* __restrict__ q, const float* __restrict__ k,
                        const float* __restrict__ v, const float* __restrict__ wq,
                        const float* __restrict__ wk, const float* __restrict__ wv,
                        const float* __restrict__ wo, _Float16* __restrict__ qh,
                        _Float16* __restrict__ kh, _Float16* __restrict__ vh,
                        _Float16* __restrict__ wqh, _Float16* __restrict__ wkh,
                        _Float16* __restrict__ wvh, _Float16* __restrict__ woh) {
    int z = blockIdx.y;
    const float* src;
    _Float16* dst;
    int n;
    switch (z) {
    case 0: src = q;  dst = qh;  n = SEQ * DM; break;
    case 1: src = k;  dst = kh;  n = SEQ * DM; break;
    case 2: src = v;  dst = vh;  n = SEQ * DM; break;
    case 3: src = wq; dst = wqh; n = DM * DM;  break;
    case 4: src = wk; dst = wkh; n = DM * DM;  break;
    case 5: src = wv; dst = wvh; n = DM * DM;  break;
    default: src = wo; dst = woh; n = DM * DM; break;
    }
    int idx = (blockIdx.x * 256 + threadIdx.x) * 4;
    if (idx >= n) return;
    float4 f = *(const float4*)(src + idx);
    half4v h;
    h[0] = (_Float16)f.x; h[1] = (_Float16)f.y; h[2] = (_Float16)f.z; h[3] = (_Float16)f.w;
    *(half4v*)(dst + idx) = h;
}

// ---------------- pipelined f16 GEMM main loop: acc += A[64-tile] @ B[NT-tile]^T --------
// Double-buffered LDS staging via global_load_lds; raw s_barrier + manual s_waitcnt
// vmcnt(0) (m139 technique) so prefetch for tile k+1 is in flight across tile-k compute.
// One barrier/iter: arrival at barrier i implies all waves finished compute i-1 (their
// waitcnt precedes it), so the buffer being overwritten is no longer read.
template <int NT>  // N-tile: 128 or 64
__device__ __forceinline__ void gemm64_loop(const _Float16* __restrict__ A,
                                            const _Float16* __restrict__ B, int m0, int n0,
                                            _Float16* As, _Float16* Bs, f32x4 (*acc)[NT / 32]) {
    constexpr int NBC = NT / 64;  // B staging chunks (64 rows x 32 cols per chunk)
    constexpr int NR = NT / 32;   // b-frags per wave
    const int tid = threadIdx.x;
    const int wave = tid >> 6, lane = tid & 63;
    const int quad = lane >> 4, l16 = lane & 15;
    const int wr = (wave >> 1) * 32;
    const int wc = (wave & 1) * (NT / 2);
    const int srow = tid >> 2, scol = (tid & 3) * 8;
    const _Float16* ga = A + (size_t)(m0 + srow) * DM + scol;
    const _Float16* gb = B + (size_t)(n0 + srow) * DM + scol;
    const int dofs = tid * 8;

    // prologue: tile 0 -> buf 0
    GLOAD_LDS(ga, As + dofs);
#pragma unroll
    for (int j = 0; j < NBC; ++j) GLOAD_LDS(gb + j * 64 * DM, Bs + j * 2048 + dofs);

    int pb = 0;
    for (int k0 = 0; k0 < DM; k0 += 32) {
        __builtin_amdgcn_s_waitcnt(0x0F70);  // vmcnt(0): own staging loads done
        __builtin_amdgcn_s_barrier();        // tile pb complete for all waves
        const int nb = pb ^ 1;
        if (k0 + 32 < DM) {  // prefetch next tile; stays in flight over this compute
            GLOAD_LDS(ga + k0 + 32, As + nb * 2048 + dofs);
#pragma unroll
            for (int j = 0; j < NBC; ++j)
                GLOAD_LDS(gb + k0 + 32 + j * 64 * DM, Bs + (nb * NBC + j) * 2048 + dofs);
        }
        const _Float16* as = As + pb * 2048;
        const _Float16* bs = Bs + pb * NBC * 2048;
        half8 af[2], bf[NR];
#pragma unroll
        for (int mi = 0; mi < 2; ++mi)
            af[mi] = *(const half8*)&as[(wr + mi * 16 + l16) * 32 + quad * 8];
#pragma unroll
        for (int ni = 0; ni < NR; ++ni)
            bf[ni] = *(const half8*)&bs[(wc + ni * 16 + l16) * 32 + quad * 8];
#pragma unroll
        for (int mi = 0; mi < 2; ++mi)
#pragma unroll
            for (int ni = 0; ni < NR; ++ni) acc[mi][ni] = MFMA16(af[mi], bf[ni], acc[mi][ni]);
        pb = nb;
    }
}

// ---------------- QKV projections: 64x128 tiles, grid (64,8,3) = 6 blocks/CU ----------
__global__ void __launch_bounds__(256) gemm_qkv(const _Float16* __restrict__ qh,
                                                const _Float16* __restrict__ kh,
                                                const _Float16* __restrict__ vh,
                                                const _Float16* __restrict__ wqh,
                                                const _Float16* __restrict__ wkh,
                                                const _Float16* __restrict__ wvh,
                                                const float* __restrict__ bq,
                                                const float* __restrict__ bk,
                                                const float* __restrict__ bv,
                                                _Float16* __restrict__ Qo,
                                                _Float16* __restrict__ Ko,
                                                _Float16* __restrict__ Vt) {
    __shared__ _Float16 As[2 * 2048];
    __shared__ _Float16 Bs[2 * 2 * 2048];
    int z = blockIdx.z;
    const _Float16 *A, *B;
    const float* bias;
    float scale;
    if (z == 0) { A = qh; B = wqh; bias = bq; scale = 0.125f; }  // 1/sqrt(64)
    else if (z == 1) { A = kh; B = wkh; bias = bk; scale = 1.0f; }
    else { A = vh; B = wvh; bias = bv; scale = 1.0f; }

    int m0 = blockIdx.x * 64;
    int n0 = blockIdx.y * 128;
    f32x4 acc[2][4] = {};
    gemm64_loop<128>(A, B, m0, n0, As, Bs, acc);

    const int tid = threadIdx.x;
    const int wave = tid >> 6, lane = tid & 63;
    const int quad = lane >> 4, l16 = lane & 15;
    const int wr = (wave >> 1) * 32;
    const int wc = (wave & 1) * 64;
    float bs[4];
#pragma unroll
    for (int ni = 0; ni < 4; ++ni) bs[ni] = bias[n0 + wc + ni * 16 + l16];

    if (z < 2) {
        _Float16* C = (z == 0) ? Qo : Ko;
#pragma unroll
        for (int mi = 0; mi < 2; ++mi)
#pragma unroll
            for (int ni = 0; ni < 4; ++ni) {
                int m = m0 + wr + mi * 16 + quad * 4;
                int n = n0 + wc + ni * 16 + l16;
#pragma unroll
                for (int r = 0; r < 4; ++r)
                    C[(size_t)(m + r) * DM + n] = (_Float16)((acc[mi][ni][r] + bs[ni]) * scale);
            }
    } else {
#pragma unroll
        for (int mi = 0; mi < 2; ++mi)
#pragma unroll
            for (int ni = 0; ni < 4; ++ni) {
                int m = m0 + wr + mi * 16 + quad * 4;
                int n = n0 + wc + ni * 16 + l16;
                half4v p;
#pragma unroll
                for (int r = 0; r < 4; ++r) p[r] = (_Float16)(acc[mi][ni][r] + bs[ni]);
                *(half4v*)(Vt + (size_t)n * SEQ + m) = p;  // m % 4 == 0 -> 8B aligned
            }
    }
}

// ---------------- output projection: 64x64 tiles, grid (64,16) = 4 blocks/CU ----------
__global__ void __launch_bounds__(256) gemm_out(const _Float16* __restrict__ Xh,
                                                const _Float16* __restrict__ woh,
                                                const float* __restrict__ bo,
                                                float* __restrict__ out) {
    __shared__ _Float16 As[2 * 2048];
    __shared__ _Float16 Bs[2 * 2048];
    int m0 = blockIdx.x * 64;
    int n0 = blockIdx.y * 64;
    f32x4 acc[2][2] = {};
    gemm64_loop<64>(Xh, woh, m0, n0, As, Bs, acc);

    const int tid = threadIdx.x;
    const int wave = tid >> 6, lane = tid & 63;
    const int quad = lane >> 4, l16 = lane & 15;
    const int wr = (wave >> 1) * 32;
    const int wc = (wave & 1) * 32;
#pragma unroll
    for (int mi = 0; mi < 2; ++mi)
#pragma unroll
        for (int ni = 0; ni < 2; ++ni) {
            int m = m0 + wr + mi * 16 + quad * 4;
            int n = n0 + wc + ni * 16 + l16;
            float b = bo[n];
#pragma unroll
            for (int r = 0; r < 4; ++r) out[(size_t)(m + r) * DM + n] = acc[mi][ni][r] + b;
        }
}

// ---------------- windowed attention, split-K across the block's 4 waves ----------------
// One block = 16 queries of one head; wave w owns key-tiles {w, w+4, w+8}. XCD swizzle:
// gridDim.x=256 (multiple of 8) => XCD = blockIdx.x%8; remap so each XCD gets one
// contiguous 512-query span -> its K/V window (~3.2 MB over 16 heads) fits its 4 MB L2.
__global__ void __launch_bounds__(256, 2) attn_kernel(const _Float16* __restrict__ Q,
                                                      const _Float16* __restrict__ K,
                                                      const _Float16* __restrict__ Vt,
                                                      _Float16* __restrict__ X) {
    __shared__ char smem[512 + 4 * 64 * 21 * 4];
    _Float16(*Pl)[2][16][40] = (_Float16(*)[2][16][40])smem;
    float2* MS = (float2*)smem;        // [w*16 + row]
    float* Ob = (float*)(smem + 512);  // [(w*64 + lane)*21 + ni*4 + r]  (21: conflict-free)

    int tid = threadIdx.x;
    int wave = tid >> 6, lane = tid & 63;
    int quad = lane >> 4, l16 = lane & 15;
    int h = blockIdx.y;
    int bx = ((blockIdx.x & 7) << 5) + (blockIdx.x >> 3);  // XCD-contiguous q-spans
    int q0 = bx * 16;

    const _Float16* Qp = Q + (size_t)(q0 + l16) * DM + h * DK + quad * 8;
    half8 aq0 = *(const half8*)(Qp);
    half8 aq1 = *(const half8*)(Qp + 32);

    int kstart = (q0 > 127) ? ((q0 - 127) & ~31) : 0;

    // Phase 1: this wave's <=3 score tiles (register-resident, loads fully in flight)
    f32x4 s[NTW][2];
#pragma unroll
    for (int j = 0; j < NTW; ++j) {
        int kt = kstart + (wave + 4 * j) * 32;
#pragma unroll
        for (int cf = 0; cf < 2; ++cf) {
            int krow = kt + cf * 16 + l16;
            int kc = krow < SEQ ? krow : SEQ - 1;  // clamp; masked below
            const _Float16* Kp = K + (size_t)kc * DM + h * DK + quad * 8;
            half8 b0 = *(const half8*)(Kp);
            half8 b1 = *(const half8*)(Kp + 32);
            f32x4 z = {};
            z = MFMA16(aq0, b0, z);
            z = MFMA16(aq1, b1, z);
            s[j][cf] = z;
        }
    }

    // Mask + per-wave row max
#pragma unroll
    for (int j = 0; j < NTW; ++j)
#pragma unroll
        for (int cf = 0; cf < 2; ++cf) {
            int key = kstart + (wave + 4 * j) * 32 + cf * 16 + l16;
#pragma unroll
            for (int r = 0; r < 4; ++r) {
                int row = q0 + quad * 4 + r;
                bool valid = (key >= row - 127) && (key <= row + 128) && (key < SEQ);
                if (!valid) s[j][cf][r] = -1e30f;
            }
        }
    float rowM[4];
#pragma unroll
    for (int r = 0; r < 4; ++r) {
        float m = -1e30f;
#pragma unroll
        for (int j = 0; j < NTW; ++j) m = fmaxf(m, fmaxf(s[j][0][r], s[j][1][r]));
#pragma unroll
        for (int off = 1; off < 16; off <<= 1) m = fmaxf(m, __shfl_xor(m, off));
        rowM[r] = m;
    }

    // Fused exp + PV over this wave's tiles (per-wave double-buffered P slot)
    f32x4 o[4] = {};
    float sum[4] = {0.f, 0.f, 0.f, 0.f};
#pragma unroll
    for (int j = 0; j < NTW; ++j) {
        int vcol = kstart + (wave + 4 * j) * 32 + quad * 8;
        int vc = vcol < SEQ ? vcol : 0;  // P=0 beyond SEQ
#pragma unroll
        for (int r = 0; r < 4; ++r) {
            float p0 = __expf(s[j][0][r] - rowM[r]);  // masked -> 0
            float p1 = __expf(s[j][1][r] - rowM[r]);
            Pl[wave][j & 1][quad * 4 + r][l16] = (_Float16)p0;
            Pl[wave][j & 1][quad * 4 + r][l16 + 16] = (_Float16)p1;
            sum[r] += p0 + p1;
        }
        half8 ap = *(const half8*)&Pl[wave][j & 1][l16][quad * 8];
#pragma unroll
        for (int ni = 0; ni < 4; ++ni) {
            const _Float16* Vp = Vt + (size_t)(h * DK + ni * 16 + l16) * SEQ + vc;
            half8 bv = *(const half8*)(Vp);
            o[ni] = MFMA16(ap, bv, o[ni]);
        }
    }
#pragma unroll
    for (int r = 0; r < 4; ++r) {
        float sm = sum[r];
#pragma unroll
        for (int off = 1; off < 16; off <<= 1) sm += __shfl_xor(sm, off);
        sum[r] = sm;
    }

    // Publish partials (all waves' P reads done before aliased region is overwritten)
    __syncthreads();
    if (l16 == 0) {
#pragma unroll
        for (int r = 0; r < 4; ++r)
            MS[wave * 16 + quad * 4 + r] = make_float2(rowM[r], sum[r]);
    }
#pragma unroll
    for (int ni = 0; ni < 4; ++ni)
        *(f32x4*)&Ob[(wave * 64 + lane) * 21 + ni * 4] = o[ni];
    __syncthreads();

    // Merge: wave w finalizes output columns ni = w (flash-decoding combine)
    int niq = wave;
    float f[4][4], rinv[4];
#pragma unroll
    for (int r = 0; r < 4; ++r) {
        float2 msv[4];
        float M = -1e30f;
#pragma unroll
        for (int w = 0; w < 4; ++w) {
            msv[w] = MS[w * 16 + quad * 4 + r];
            M = fmaxf(M, msv[w].x);
        }
        float S = 0.f;
#pragma unroll
        for (int w = 0; w < 4; ++w) {
            f[w][r] = __expf(msv[w].x - M);  // empty-partial: exp(-huge)=0
            S += f[w][r] * msv[w].y;
        }
        rinv[r] = 1.0f / S;
    }
    f32x4 acc = {};
#pragma unroll
    for (int w = 0; w < 4; ++w) {
        f32x4 ov = *(const f32x4*)&Ob[(w * 64 + lane) * 21 + niq * 4];
#pragma unroll
        for (int r = 0; r < 4; ++r) acc[r] += f[w][r] * ov[r];
    }
#pragma unroll
    for (int r = 0; r < 4; ++r) {
        int m = q0 + quad * 4 + r;
        X[(size_t)m * DM + h * DK + niq * 16 + l16] = (_Float16)(acc[r] * rinv[r]);
    }
}

extern "C" void kernel_launch(void* const* d_in, const int* in_sizes, int n_in, void* d_out,
                              int out_size, void* d_ws, size_t ws_size, hipStream_t stream) {
    const float* q  = (const float*)d_in[0];
    const float* k  = (const float*)d_in[1];
    const float* v  = (const float*)d_in[2];
    const float* wq = (const float*)d_in[3];
    const float* bq = (const float*)d_in[4];
    const float* wk = (const float*)d_in[5];
    const float* bk = (const float*)d_in[6];
    const float* wv = (const float*)d_in[7];
    const float* bv = (const float*)d_in[8];
    const float* wo = (const float*)d_in[9];
    const float* bo = (const float*)d_in[10];

    const size_t SZ_T = (size_t)SEQ * DM * sizeof(_Float16);  // 8 MB
    const size_t SZ_W = (size_t)DM * DM * sizeof(_Float16);   // 2 MB
    char* p = (char*)d_ws;
    _Float16* qh  = (_Float16*)(p);
    _Float16* kh  = (_Float16*)(p + SZ_T);
    _Float16* vh  = (_Float16*)(p + 2 * SZ_T);
    _Float16* wqh = (_Float16*)(p + 3 * SZ_T);
    _Float16* wkh = (_Float16*)(p + 3 * SZ_T + SZ_W);
    _Float16* wvh = (_Float16*)(p + 3 * SZ_T + 2 * SZ_W);
    _Float16* woh = (_Float16*)(p + 3 * SZ_T + 3 * SZ_W);
    _Float16* Qo  = (_Float16*)(p + 3 * SZ_T + 4 * SZ_W);
    _Float16* Ko  = (_Float16*)(p + 4 * SZ_T + 4 * SZ_W);
    _Float16* Vt  = (_Float16*)(p + 5 * SZ_T + 4 * SZ_W);
    _Float16* Xh  = qh;  // alias: qh dead after gemm_qkv (stream-serialized)

    cvt_all<<<dim3(4096, 7), 256, 0, stream>>>(q, k, v, wq, wk, wv, wo, qh, kh, vh, wqh, wkh,
                                               wvh, woh);
    gemm_qkv<<<dim3(64, 8, 3), 256, 0, stream>>>(qh, kh, vh, wqh, wkh, wvh, bq, bk, bv, Qo, Ko,
                                                 Vt);
    attn_kernel<<<dim3(SEQ / 16, NH), 256, 0, stream>>>(Qo, Ko, Vt, Xh);
    gemm_out<<<dim3(64, 16), 256, 0, stream>>>(Xh, woh, bo, (float*)d_out);
}

// Round 6
// 213.565 us; speedup vs baseline: 1.1602x; 1.1602x over previous
//
#include <hip/hip_runtime.h>

#define SEQ 4096
#define DM 1024
#define NH 16
#define DK 64

typedef _Float16 half8 __attribute__((ext_vector_type(8)));
typedef _Float16 half4v __attribute__((ext_vector_type(4)));
typedef float f32x4 __attribute__((ext_vector_type(4)));

#define MFMA16(a, b, c) __builtin_amdgcn_mfma_f32_16x16x32_f16((a), (b), (c), 0, 0, 0)
#define GLOAD_LDS(g, l)                                                                  \
    __builtin_amdgcn_global_load_lds((const __attribute__((address_space(1))) void*)(g), \
                                     (__attribute__((address_space(3))) void*)(l), 16, 0, 0)

// ---------------- fp32 -> fp16 conversion (7 tensors in one launch) ----------------
__global__ void cvt_all(const float* __restrict__ q, const float* __restrict__ k,
                        const float* __restrict__ v, const float* __restrict__ wq,
                        const float* __restrict__ wk, const float* __restrict__ wv,
                        const float* __restrict__ wo, _Float16* __restrict__ qh,
                        _Float16* __restrict__ kh, _Float16* __restrict__ vh,
                        _Float16* __restrict__ wqh, _Float16* __restrict__ wkh,
                        _Float16* __restrict__ wvh, _Float16* __restrict__ woh) {
    int z = blockIdx.y;
    const float* src;
    _Float16* dst;
    int n;
    switch (z) {
    case 0: src = q;  dst = qh;  n = SEQ * DM; break;
    case 1: src = k;  dst = kh;  n = SEQ * DM; break;
    case 2: src = v;  dst = vh;  n = SEQ * DM; break;
    case 3: src = wq; dst = wqh; n = DM * DM;  break;
    case 4: src = wk; dst = wkh; n = DM * DM;  break;
    case 5: src = wv; dst = wvh; n = DM * DM;  break;
    default: src = wo; dst = woh; n = DM * DM; break;
    }
    int idx = (blockIdx.x * 256 + threadIdx.x) * 4;
    if (idx >= n) return;
    float4 f = *(const float4*)(src + idx);
    half4v h;
    h[0] = (_Float16)f.x; h[1] = (_Float16)f.y; h[2] = (_Float16)f.z; h[3] = (_Float16)f.w;
    *(half4v*)(dst + idx) = h;
}

// ---------------- m97-structure f16 GEMM, BK=64: acc += A[MTx64] @ B[128x64]^T ----------
// 2-barrier K-loop (verified structure), 16 iterations at K=1024 (BK=32 had 32 barrier
// drains; m132's BK=128 regression was the 64KB-LDS occupancy cliff -- 32KB avoids it).
// LDS layout: panels [2][rows][32] so each 32-col panel keeps the verified b128 frag read.
template <int MT>  // M-tile: 128 (qkv) or 64 (out); N-tile fixed 128
__device__ __forceinline__ void gemm_bk64(const _Float16* __restrict__ A,
                                          const _Float16* __restrict__ B, int m0, int n0,
                                          _Float16* As, _Float16* Bs, f32x4 (*acc)[4]) {
    constexpr int MI = MT / 32;   // A row-frags per wave
    constexpr int ACH = MT / 64;  // 64-row staging chunks per A panel
    const int tid = threadIdx.x;
    const int wave = tid >> 6, lane = tid & 63;
    const int quad = lane >> 4, l16 = lane & 15;
    const int wr = (wave >> 1) * (MT / 2);
    const int wc = (wave & 1) * 64;
    const int srow = tid >> 2, scol = (tid & 3) * 8;

    for (int k0 = 0; k0 < DM; k0 += 64) {
#pragma unroll
        for (int p = 0; p < 2; ++p) {
            int kc = k0 + p * 32 + scol;
#pragma unroll
            for (int j = 0; j < ACH; ++j)
                GLOAD_LDS(A + (size_t)(m0 + j * 64 + srow) * DM + kc,
                          As + p * (MT * 32) + j * 2048 + tid * 8);
#pragma unroll
            for (int j = 0; j < 2; ++j)
                GLOAD_LDS(B + (size_t)(n0 + j * 64 + srow) * DM + kc,
                          Bs + p * 4096 + j * 2048 + tid * 8);
        }
        __syncthreads();
#pragma unroll
        for (int p = 0; p < 2; ++p) {
            half8 af[MI], bf[4];
#pragma unroll
            for (int mi = 0; mi < MI; ++mi)
                af[mi] = *(const half8*)&As[p * (MT * 32) + (wr + mi * 16 + l16) * 32 + quad * 8];
#pragma unroll
            for (int ni = 0; ni < 4; ++ni)
                bf[ni] = *(const half8*)&Bs[p * 4096 + (wc + ni * 16 + l16) * 32 + quad * 8];
#pragma unroll
            for (int mi = 0; mi < MI; ++mi)
#pragma unroll
                for (int ni = 0; ni < 4; ++ni)
                    acc[mi][ni] = MFMA16(af[mi], bf[ni], acc[mi][ni]);
        }
        __syncthreads();
    }
}

// ---------------- QKV projections: 128x128 tiles, grid (32,8,3) = 3 blocks/CU ----------
__global__ void __launch_bounds__(256, 3) gemm_qkv(
    const _Float16* __restrict__ qh, const _Float16* __restrict__ kh,
    const _Float16* __restrict__ vh, const _Float16* __restrict__ wqh,
    const _Float16* __restrict__ wkh, const _Float16* __restrict__ wvh,
    const float* __restrict__ bq, const float* __restrict__ bk, const float* __restrict__ bv,
    _Float16* __restrict__ Qo, _Float16* __restrict__ Ko, _Float16* __restrict__ Vt) {
    __shared__ _Float16 As[2 * 128 * 32];
    __shared__ _Float16 Bs[2 * 128 * 32];
    int z = blockIdx.z;
    const _Float16 *A, *B;
    const float* bias;
    float scale;
    if (z == 0) { A = qh; B = wqh; bias = bq; scale = 0.125f; }  // 1/sqrt(64)
    else if (z == 1) { A = kh; B = wkh; bias = bk; scale = 1.0f; }
    else { A = vh; B = wvh; bias = bv; scale = 1.0f; }

    int m0 = blockIdx.x * 128;
    int n0 = blockIdx.y * 128;
    f32x4 acc[4][4] = {};
    gemm_bk64<128>(A, B, m0, n0, As, Bs, acc);

    const int tid = threadIdx.x;
    const int wave = tid >> 6, lane = tid & 63;
    const int quad = lane >> 4, l16 = lane & 15;
    const int wr = (wave >> 1) * 64;
    const int wc = (wave & 1) * 64;
    float bs[4];
#pragma unroll
    for (int ni = 0; ni < 4; ++ni) bs[ni] = bias[n0 + wc + ni * 16 + l16];

    if (z < 2) {
        _Float16* C = (z == 0) ? Qo : Ko;
#pragma unroll
        for (int mi = 0; mi < 4; ++mi)
#pragma unroll
            for (int ni = 0; ni < 4; ++ni) {
                int m = m0 + wr + mi * 16 + quad * 4;
                int n = n0 + wc + ni * 16 + l16;
#pragma unroll
                for (int r = 0; r < 4; ++r)
                    C[(size_t)(m + r) * DM + n] = (_Float16)((acc[mi][ni][r] + bs[ni]) * scale);
            }
    } else {
#pragma unroll
        for (int mi = 0; mi < 4; ++mi)
#pragma unroll
            for (int ni = 0; ni < 4; ++ni) {
                int m = m0 + wr + mi * 16 + quad * 4;
                int n = n0 + wc + ni * 16 + l16;
                half4v p;
#pragma unroll
                for (int r = 0; r < 4; ++r) p[r] = (_Float16)(acc[mi][ni][r] + bs[ni]);
                *(half4v*)(Vt + (size_t)n * SEQ + m) = p;  // m % 4 == 0 -> 8B aligned
            }
    }
}

// ---------------- output projection: 64x128 tiles, grid (64,8) = 2 blocks/CU ----------
__global__ void __launch_bounds__(256, 3) gemm_out(const _Float16* __restrict__ Xh,
                                                   const _Float16* __restrict__ woh,
                                                   const float* __restrict__ bo,
                                                   float* __restrict__ out) {
    __shared__ _Float16 As[2 * 64 * 32];
    __shared__ _Float16 Bs[2 * 128 * 32];
    int m0 = blockIdx.x * 64;
    int n0 = blockIdx.y * 128;
    f32x4 acc[2][4] = {};
    gemm_bk64<64>(Xh, woh, m0, n0, As, Bs, acc);

    const int tid = threadIdx.x;
    const int wave = tid >> 6, lane = tid & 63;
    const int quad = lane >> 4, l16 = lane & 15;
    const int wr = (wave >> 1) * 32;
    const int wc = (wave & 1) * 64;
#pragma unroll
    for (int mi = 0; mi < 2; ++mi)
#pragma unroll
        for (int ni = 0; ni < 4; ++ni) {
            int m = m0 + wr + mi * 16 + quad * 4;
            int n = n0 + wc + ni * 16 + l16;
            float b = bo[n];
#pragma unroll
            for (int r = 0; r < 4; ++r) out[(size_t)(m + r) * DM + n] = acc[mi][ni][r] + b;
        }
}

// ---------------- windowed attention: R1 online-softmax (best measured) + XCD swizzle --
// One wave = 16 queries of one head, barrier-free online loop over <=10 32-key tiles.
// Swizzle: gridDim.x=64, XCD = blockIdx.x%8 (dispatch round-robin); remap so each XCD
// gets one contiguous 512-query span -> its K/V working set (~4 MB) fits its private L2
// (R5 evidence: FETCH 72->17.5 MB from this swizzle alone).
__global__ void attn_kernel(const _Float16* __restrict__ Q, const _Float16* __restrict__ K,
                            const _Float16* __restrict__ Vt, _Float16* __restrict__ X) {
    __shared__ _Float16 Pl[4][16][32];
    int tid = threadIdx.x;
    int wave = tid >> 6, lane = tid & 63;
    int quad = lane >> 4, l16 = lane & 15;
    int h = blockIdx.y;
    int bx = ((blockIdx.x & 7) << 3) + (blockIdx.x >> 3);  // XCD-contiguous q-spans
    int q0 = bx * 64 + wave * 16;

    const _Float16* Qp = Q + (size_t)(q0 + l16) * DM + h * DK + quad * 8;
    half8 aq0 = *(const half8*)(Qp);
    half8 aq1 = *(const half8*)(Qp + 32);

    float rowM[4], rowL[4];
    f32x4 o[4] = {};
#pragma unroll
    for (int r = 0; r < 4; ++r) { rowM[r] = -__builtin_inff(); rowL[r] = 0.f; }

    int kstart = (q0 > 127) ? ((q0 - 127) & ~31) : 0;
    int kend = q0 + 143;
    if (kend > SEQ - 1) kend = SEQ - 1;

    for (int kt = kstart; kt <= kend; kt += 32) {
        f32x4 s[2];
#pragma unroll
        for (int cf = 0; cf < 2; ++cf) {
            int krow = kt + cf * 16 + l16;  // < SEQ (32-aligned tiles, SEQ % 32 == 0)
            const _Float16* Kp = K + (size_t)krow * DM + h * DK + quad * 8;
            half8 b0 = *(const half8*)(Kp);
            half8 b1 = *(const half8*)(Kp + 32);
            f32x4 z = {};
            z = MFMA16(aq0, b0, z);
            z = MFMA16(aq1, b1, z);
            s[cf] = z;
        }
        float mnew[4], alpha[4];
#pragma unroll
        for (int r = 0; r < 4; ++r) {
            int row = q0 + quad * 4 + r;
#pragma unroll
            for (int cf = 0; cf < 2; ++cf) {
                int key = kt + cf * 16 + l16;
                bool valid = (key >= row - 127) && (key <= row + 128);
                if (!valid) s[cf][r] = -1e30f;
            }
            float t = fmaxf(s[0][r], s[1][r]);
#pragma unroll
            for (int off = 1; off < 16; off <<= 1) t = fmaxf(t, __shfl_xor(t, off));
            mnew[r] = fmaxf(rowM[r], t);
            alpha[r] = __expf(rowM[r] - mnew[r]);  // exp(-inf - finite) = 0 on first tile
            float p0 = __expf(s[0][r] - mnew[r]);
            float p1 = __expf(s[1][r] - mnew[r]);
            Pl[wave][quad * 4 + r][l16] = (_Float16)p0;
            Pl[wave][quad * 4 + r][l16 + 16] = (_Float16)p1;
            float rs = p0 + p1;
#pragma unroll
            for (int off = 1; off < 16; off <<= 1) rs += __shfl_xor(rs, off);
            rowL[r] = rowL[r] * alpha[r] + rs;
            rowM[r] = mnew[r];
        }
#pragma unroll
        for (int ni = 0; ni < 4; ++ni)
#pragma unroll
            for (int r = 0; r < 4; ++r) o[ni][r] *= alpha[r];
        // P: C-layout -> A-operand layout via per-wave LDS round-trip (wave-internal)
        half8 ap = *(const half8*)&Pl[wave][l16][quad * 8];
#pragma unroll
        for (int ni = 0; ni < 4; ++ni) {
            const _Float16* Vp = Vt + (size_t)(h * DK + ni * 16 + l16) * SEQ + kt + quad * 8;
            half8 bv = *(const half8*)(Vp);
            o[ni] = MFMA16(ap, bv, o[ni]);
        }
    }

    float rinv[4];
#pragma unroll
    for (int r = 0; r < 4; ++r) rinv[r] = 1.0f / rowL[r];
#pragma unroll
    for (int ni = 0; ni < 4; ++ni) {
        int n = h * DK + ni * 16 + l16;
#pragma unroll
        for (int r = 0; r < 4; ++r) {
            int m = q0 + quad * 4 + r;
            X[(size_t)m * DM + n] = (_Float16)(o[ni][r] * rinv[r]);
        }
    }
}

extern "C" void kernel_launch(void* const* d_in, const int* in_sizes, int n_in, void* d_out,
                              int out_size, void* d_ws, size_t ws_size, hipStream_t stream) {
    const float* q  = (const float*)d_in[0];
    const float* k  = (const float*)d_in[1];
    const float* v  = (const float*)d_in[2];
    const float* wq = (const float*)d_in[3];
    const float* bq = (const float*)d_in[4];
    const float* wk = (const float*)d_in[5];
    const float* bk = (const float*)d_in[6];
    const float* wv = (const float*)d_in[7];
    const float* bv = (const float*)d_in[8];
    const float* wo = (const float*)d_in[9];
    const float* bo = (const float*)d_in[10];

    const size_t SZ_T = (size_t)SEQ * DM * sizeof(_Float16);  // 8 MB
    const size_t SZ_W = (size_t)DM * DM * sizeof(_Float16);   // 2 MB
    char* p = (char*)d_ws;
    _Float16* qh  = (_Float16*)(p);
    _Float16* kh  = (_Float16*)(p + SZ_T);
    _Float16* vh  = (_Float16*)(p + 2 * SZ_T);
    _Float16* wqh = (_Float16*)(p + 3 * SZ_T);
    _Float16* wkh = (_Float16*)(p + 3 * SZ_T + SZ_W);
    _Float16* wvh = (_Float16*)(p + 3 * SZ_T + 2 * SZ_W);
    _Float16* woh = (_Float16*)(p + 3 * SZ_T + 3 * SZ_W);
    _Float16* Qo  = (_Float16*)(p + 3 * SZ_T + 4 * SZ_W);
    _Float16* Ko  = (_Float16*)(p + 4 * SZ_T + 4 * SZ_W);
    _Float16* Vt  = (_Float16*)(p + 5 * SZ_T + 4 * SZ_W);
    _Float16* Xh  = qh;  // alias: qh dead after gemm_qkv (stream-serialized)

    cvt_all<<<dim3(4096, 7), 256, 0, stream>>>(q, k, v, wq, wk, wv, wo, qh, kh, vh, wqh, wkh,
                                               wvh, woh);
    gemm_qkv<<<dim3(32, 8, 3), 256, 0, stream>>>(qh, kh, vh, wqh, wkh, wvh, bq, bk, bv, Qo, Ko,
                                                 Vt);
    attn_kernel<<<dim3(SEQ / 64, NH), 256, 0, stream>>>(Qo, Ko, Vt, Xh);
    gemm_out<<<dim3(64, 8), 256, 0, stream>>>(Xh, woh, bo, (float*)d_out);
}